// Round 5
// baseline (226469.409 us; speedup 1.0000x reference)
//
#include <hip/hip_runtime.h>
#include <hip/hip_cooperative_groups.h>
#include <math.h>

namespace cg = cooperative_groups;

#define Z_DIM   256
#define HID     1024
#define VOCAB   512
#define SEQ_LEN 512
#define BATCH   64
#define NBLK    256
#define NTHR    1024
#define CHUNK   128

// ws float offsets
#define WS_EXPT  0             // [VOCAB][64] softmax probs (pre-normalized)
#define WS_H0A   32768         // [HID][64]
#define WS_H0B   98304
#define WS_H1A   163840
#define WS_H1B   229376
#define WS_C0    294912
#define WS_C1    360448
#define WS_B0    425984        // [4*HID] combined bias l0
#define WS_B1    430080        // [4*HID] combined bias l1

__device__ __forceinline__ float sigm(float x) { return 1.f / (1.f + expf(-x)); }

// One gate-GEMM segment. Block owns 16 gate-rows (4 units x 4 gates) of w.
// Wave (u2,s) accumulates 8 rows (units u2*2,u2*2+1) over k-slice s (16 of
// each 128-chunk). Acts src [K][64]; lane = batch. acc[j] -> row16 = u2*8+j.
__device__ __forceinline__ void seg(
    const float* __restrict__ w, int K,
    const float* __restrict__ src, int nc,
    int rbase, int u2, int s, int tid, int lane,
    float* __restrict__ sA, float* __restrict__ sW, float* __restrict__ acc)
{
    float4 a0, a1, vw;
    const int wrow = tid >> 5;            // 0..15 for tid<512
    const int wcol = (tid & 31) << 2;

    auto pre = [&](int c) {               // global -> regs (no LDS)
        const float4* g4 = (const float4*)(src + (size_t)(c * CHUNK) * 64);
        a0 = g4[tid];
        a1 = g4[tid + 1024];
        if (tid < 512) {
            const int g = wrow & 3, u = wrow >> 2;
            vw = *(const float4*)(w + (size_t)(g * HID + rbase + u) * K + c * CHUNK + wcol);
        }
    };

    pre(0);
    for (int c = 0; c < nc; ++c) {
        __syncthreads();                  // (A) all done reading sA/sW
        {
            float4* dA = (float4*)sA;
            dA[tid]        = a0;
            dA[tid + 1024] = a1;
            if (tid < 512) *(float4*)&sW[wrow * CHUNK + wcol] = vw;
        }
        __syncthreads();                  // (B) staged data visible
        if (c + 1 < nc) pre(c + 1);       // prefetch hides under comp
        const float* As = sA + s * 16 * 64 + lane;
        const float* Wr = sW + (u2 * 8) * CHUNK + s * 16;
#pragma unroll
        for (int q = 0; q < 4; ++q) {
            const float x0 = As[(4 * q + 0) * 64];
            const float x1 = As[(4 * q + 1) * 64];
            const float x2 = As[(4 * q + 2) * 64];
            const float x3 = As[(4 * q + 3) * 64];
#pragma unroll
            for (int j = 0; j < 8; ++j) {
                const float4 wv = *(const float4*)&Wr[j * CHUNK + 4 * q];
                acc[j] = fmaf(wv.x, x0, fmaf(wv.y, x1, fmaf(wv.z, x2, fmaf(wv.w, x3, acc[j]))));
            }
        }
    }
}

__global__ __launch_bounds__(NTHR, 4) void lstm_persistent(
    const float* __restrict__ z,     const float* __restrict__ fc_w,
    const float* __restrict__ fc_b,  const float* __restrict__ w_ih0,
    const float* __restrict__ w_hh0, const float* __restrict__ b_ih0,
    const float* __restrict__ b_hh0, const float* __restrict__ w_ih1,
    const float* __restrict__ w_hh1, const float* __restrict__ b_ih1,
    const float* __restrict__ b_hh1, const float* __restrict__ out_w,
    const float* __restrict__ out_b, float* __restrict__ out,
    float* __restrict__ ws)
{
    cg::grid_group grid = cg::this_grid();
    const int tid  = threadIdx.x;
    const int lane = tid & 63;
    const int widx = tid >> 6;            // 0..15
    const int u2   = widx >> 3;           // 0..1 : unit-pair
    const int s    = widx & 7;            // 0..7 : k-slice
    const int bid  = blockIdx.x;
    const int rbase = bid * 4;            // first unit of this block

    float* expT = ws + WS_EXPT;
    float* h0A  = ws + WS_H0A;
    float* h0B  = ws + WS_H0B;
    float* h1A  = ws + WS_H1A;
    float* h1B  = ws + WS_H1B;
    float* c0T  = ws + WS_C0;
    float* c1T  = ws + WS_C1;
    float* b0v  = ws + WS_B0;
    float* b1v  = ws + WS_B1;

    __shared__ float sA[64 * CHUNK];      // 32 KB: act chunk / partial overlay
    __shared__ float sW[16 * CHUNK];      // 8 KB: 16 gate-rows
    __shared__ float sG[16 * 64];         // 4 KB: reduced gates
    __shared__ float h1s[HID];            // 4 KB: P2 h column
    __shared__ float sred[16];

    // ---------------- init ----------------
    {
        const int gtid = bid * NTHR + tid;
        if (gtid < 4096)        b0v[gtid] = b_ih0[gtid] + b_hh0[gtid];
        else if (gtid < 8192) { const int n = gtid - 4096; b1v[n] = b_ih1[n] + b_hh1[n]; }
        if (gtid < 32768) expT[gtid] = 0.f;
        if (widx < 4) {                   // waves 0..3: h_init for 4 units
            const int ju = rbase + widx;
            const float4* wr = (const float4*)(fc_w + (size_t)ju * Z_DIM);
            const float4* zr = (const float4*)(z + (size_t)lane * Z_DIM);
            float acc = 0.f;
#pragma unroll 4
            for (int k4 = 0; k4 < Z_DIM / 4; ++k4) {
                const float4 a = wr[k4];
                const float4 x = zr[k4];
                acc = fmaf(a.x, x.x, fmaf(a.y, x.y, fmaf(a.z, x.z, fmaf(a.w, x.w, acc))));
            }
            const float h = tanhf(acc + fc_b[ju]);
            const int ci = (ju << 6) + lane;
            h0A[ci] = h; h1A[ci] = h; c0T[ci] = 0.f; c1T[ci] = 0.f;
        }
    }
    grid.sync();

    for (int t = 0; t < SEQ_LEN; ++t) {
        const int par = t & 1;
        const float* h0_r = par ? h0B : h0A;
        float*       h0_w = par ? h0A : h0B;
        const float* h1_r = par ? h1B : h1A;
        float*       h1_w = par ? h1A : h1B;

        // ---------------- P0: layer0 ----------------
        {
            float acc[8] = {0, 0, 0, 0, 0, 0, 0, 0};
            seg(w_ih0, VOCAB, expT, 4, rbase, u2, s, tid, lane, sA, sW, acc);
            seg(w_hh0, HID, h0_r, 8, rbase, u2, s, tid, lane, sA, sW, acc);
            __syncthreads();              // all comps done before overlay
#pragma unroll
            for (int j = 0; j < 8; ++j)
                sA[(u2 * 8 + j) * 512 + s * 64 + lane] = acc[j];
            __syncthreads();
            {
                const int r16 = tid >> 6, b = tid & 63;
                const int g = r16 & 3, u = r16 >> 2;
                float v = b0v[g * HID + rbase + u];
#pragma unroll
                for (int ss = 0; ss < 8; ++ss) v += sA[r16 * 512 + ss * 64 + b];
                sG[r16 * 64 + b] = v;
            }
            __syncthreads();
            if (tid < 256) {
                const int u = tid >> 6, b = tid & 63;
                const int ju = rbase + u;
                const float i_ = sigm(sG[(u * 4 + 0) * 64 + b]);
                const float f_ = sigm(sG[(u * 4 + 1) * 64 + b]);
                const float g_ = tanhf(sG[(u * 4 + 2) * 64 + b]);
                const float o_ = sigm(sG[(u * 4 + 3) * 64 + b]);
                const int ci = (ju << 6) + b;
                const float cn = fmaf(f_, c0T[ci], i_ * g_);
                c0T[ci]  = cn;
                h0_w[ci] = o_ * tanhf(cn);
            }
        }
        grid.sync();

        // ---------------- P1: layer1 ----------------
        {
            float acc[8] = {0, 0, 0, 0, 0, 0, 0, 0};
            seg(w_ih1, HID, h0_w, 8, rbase, u2, s, tid, lane, sA, sW, acc);
            seg(w_hh1, HID, h1_r, 8, rbase, u2, s, tid, lane, sA, sW, acc);
            __syncthreads();
#pragma unroll
            for (int j = 0; j < 8; ++j)
                sA[(u2 * 8 + j) * 512 + s * 64 + lane] = acc[j];
            __syncthreads();
            {
                const int r16 = tid >> 6, b = tid & 63;
                const int g = r16 & 3, u = r16 >> 2;
                float v = b1v[g * HID + rbase + u];
#pragma unroll
                for (int ss = 0; ss < 8; ++ss) v += sA[r16 * 512 + ss * 64 + b];
                sG[r16 * 64 + b] = v;
            }
            __syncthreads();
            if (tid < 256) {
                const int u = tid >> 6, b = tid & 63;
                const int ju = rbase + u;
                const float i_ = sigm(sG[(u * 4 + 0) * 64 + b]);
                const float f_ = sigm(sG[(u * 4 + 1) * 64 + b]);
                const float g_ = tanhf(sG[(u * 4 + 2) * 64 + b]);
                const float o_ = sigm(sG[(u * 4 + 3) * 64 + b]);
                const int ci = (ju << 6) + b;
                const float cn = fmaf(f_, c1T[ci], i_ * g_);
                c1T[ci]  = cn;
                h1_w[ci] = o_ * tanhf(cn);
            }
        }
        grid.sync();

        // ---------------- P2: logits + softmax (blocks 0..63) ----------------
        if (bid < BATCH) {
            const int b = bid;
            h1s[tid] = h1_w[(size_t)tid * 64 + b];
            __syncthreads();
            float l = 0.f, e = 0.f;
            if (tid < 512) {
                const int v = tid;
                const float4* r0 = (const float4*)(out_w + (size_t)v * HID);
#pragma unroll 4
                for (int k4 = 0; k4 < HID / 4; ++k4) {
                    const float4 h = *(const float4*)&h1s[k4 << 2];  // broadcast
                    const float4 a = r0[k4];
                    l = fmaf(a.x, h.x, l);
                    l = fmaf(a.y, h.y, l);
                    l = fmaf(a.z, h.z, l);
                    l = fmaf(a.w, h.w, l);
                }
                l += out_b[v];
                out[((size_t)b * SEQ_LEN + t) * VOCAB + v] = l;
                float m = l;
#pragma unroll
                for (int off = 32; off; off >>= 1) m = fmaxf(m, __shfl_xor(m, off));
                if (lane == 0) sred[widx] = m;
            }
            __syncthreads();
            if (tid < 512) {
                float M = sred[0];
#pragma unroll
                for (int i = 1; i < 8; ++i) M = fmaxf(M, sred[i]);
                e = expf(l - M);
                float ssum = e;
#pragma unroll
                for (int off = 32; off; off >>= 1) ssum += __shfl_xor(ssum, off);
                if (lane == 0) sred[8 + widx] = ssum;
            }
            __syncthreads();
            if (tid < 512) {
                float S = sred[8];
#pragma unroll
                for (int i = 1; i < 8; ++i) S += sred[8 + i];
                expT[(size_t)tid * 64 + b] = e * (1.f / S);   // normalized probs
            }
        }
        grid.sync();
    }
}

extern "C" void kernel_launch(void* const* d_in, const int* in_sizes, int n_in,
                              void* d_out, int out_size, void* d_ws, size_t ws_size,
                              hipStream_t stream) {
    (void)in_sizes; (void)n_in; (void)out_size; (void)ws_size;
    const float* z     = (const float*)d_in[0];
    const float* fc_w  = (const float*)d_in[1];
    const float* fc_b  = (const float*)d_in[2];
    const float* w_ih0 = (const float*)d_in[3];
    const float* w_hh0 = (const float*)d_in[4];
    const float* b_ih0 = (const float*)d_in[5];
    const float* b_hh0 = (const float*)d_in[6];
    const float* w_ih1 = (const float*)d_in[7];
    const float* w_hh1 = (const float*)d_in[8];
    const float* b_ih1 = (const float*)d_in[9];
    const float* b_hh1 = (const float*)d_in[10];
    const float* out_w = (const float*)d_in[11];
    const float* out_b = (const float*)d_in[12];
    float* out = (float*)d_out;
    float* ws  = (float*)d_ws;

    void* args[] = { &z, &fc_w, &fc_b, &w_ih0, &w_hh0, &b_ih0, &b_hh0,
                     &w_ih1, &w_hh1, &b_ih1, &b_hh1, &out_w, &out_b, &out, &ws };
    hipLaunchCooperativeKernel((const void*)lstm_persistent,
                               dim3(NBLK), dim3(NTHR), args, 0, stream);
}